// Round 1
// baseline (80.498 us; speedup 1.0000x reference)
//
#include <hip/hip_runtime.h>

// ROIAlign3d: input [2,1024,32,16,16] f32, rois [32,5] f32 -> out [32,1024,32,7,7] f32
// Design:
//  - grid = 2048 blocks, each owns 16 consecutive (c,l) planes.
//  - stage both batches' 16 planes (2*16*1KB) into LDS, transposed to
//    [cell=y*16+x][b*16+p] so taps are float4 loads across 4 planes.
//  - bilinear + 2x2-sample average factorizes per bin into a 4x4 outer
//    product of per-axis (index,weight) pairs -> 16 taps/output.
//  - tap tables (per roi, per axis sample: i0,i1,w0,w1 with validity and
//    the 1/4 mean folded in) precomputed once per block into LDS.
//  - every input byte read from HBM exactly once; outputs written once.

constexpr int kPH = 7, kPW = 7, kSR = 2;
constexpr float kSCALE = 0.0625f;
constexpr int kNB = 2, kNC = 1024, kNL = 32, kNH = 16, kNW = 16;
constexpr int kCL = kNC * kNL;           // 32768
constexpr int kNROI = 32;
constexpr int kPPB = 16;                 // (c,l) planes per block
constexpr int kTPB = 256;
constexpr int kNSAMP = kPH * kSR;        // 14 samples per axis
constexpr int kCSTR = 2 * kPPB + 4;      // 36 floats per (y,x) cell (pad 4: 16B-aligned, bank-rotating)
constexpr int kNBIN = kPH * kPW;         // 49

__global__ __launch_bounds__(kTPB) void roialign3d_kernel(
    const float* __restrict__ input, const float* __restrict__ rois,
    float* __restrict__ out)
{
    __shared__ float sp[256 * kCSTR];                      // 36864 B: [cell][b*16+p]
    __shared__ float syw0[kNROI * kNSAMP], syw1[kNROI * kNSAMP];
    __shared__ float sxw0[kNROI * kNSAMP], sxw1[kNROI * kNSAMP];
    __shared__ int   syi0[kNROI * kNSAMP], syi1[kNROI * kNSAMP];
    __shared__ int   sxi0[kNROI * kNSAMP], sxi1[kNROI * kNSAMP];
    __shared__ int   sbidx[kNROI];

    const int cl0 = blockIdx.x * kPPB;
    const int tid = threadIdx.x;

    // ---- stage planes: 2 batches x 16 planes x 256 floats, transposed ----
    {
        const int pi = tid >> 3;                           // 0..31 = b*16+p
        const int bb = pi >> 4, p = pi & 15;
        const float4* src = reinterpret_cast<const float4*>(
            input + (size_t)(bb * kCL + cl0 + p) * (kNH * kNW));
        #pragma unroll
        for (int j = 0; j < 8; ++j) {
            const int f = (tid & 7) + j * 8;               // float4 index 0..63
            const float4 v = src[f];
            const int e = f * 4;                           // cell index of v.x
            sp[(e + 0) * kCSTR + pi] = v.x;
            sp[(e + 1) * kCSTR + pi] = v.y;
            sp[(e + 2) * kCSTR + pi] = v.z;
            sp[(e + 3) * kCSTR + pi] = v.w;
        }
    }

    // ---- per-roi per-axis tap tables (896 entries) ----
    for (int e = tid; e < 2 * kNROI * kNSAMP; e += kTPB) {
        const int axis = (e >= kNROI * kNSAMP) ? 1 : 0;    // 0=y, 1=x
        const int idx = axis ? (e - kNROI * kNSAMP) : e;
        const int r = idx / kNSAMP;
        const int k = idx - r * kNSAMP;
        const float lo = rois[r * 5 + (axis ? 1 : 2)] * kSCALE;
        const float hi = rois[r * 5 + (axis ? 3 : 4)] * kSCALE;
        const float sz = fmaxf(hi - lo, 1.0f);
        const float bin = sz * (1.0f / 7.0f);
        const int g = k >> 1, o = k & 1;
        const float coord = lo + (float)g * bin + ((float)o + 0.5f) * (bin * 0.5f);
        const bool valid = (coord >= -1.0f) && (coord <= 16.0f);
        const float c = fminf(fmaxf(coord, 0.0f), 15.0f);
        const int i0 = (int)floorf(c);                     // <= 15 by clamp
        const int i1 = (i0 + 1 < 16) ? i0 + 1 : 15;
        const float l = c - (float)i0;
        // fold the 1/(SR*SR)=0.25 mean as 0.5 * 0.5 into y- and x-weights
        const float w0 = valid ? (1.0f - l) * 0.5f : 0.0f;
        const float w1 = valid ? l * 0.5f : 0.0f;
        if (axis) { sxi0[idx] = i0; sxi1[idx] = i1; sxw0[idx] = w0; sxw1[idx] = w1; }
        else      { syi0[idx] = i0; syi1[idx] = i1; syw0[idx] = w0; syw1[idx] = w1; }
    }
    if (tid < kNROI) sbidx[tid] = (int)rois[tid * 5];
    __syncthreads();

    // ---- compute: 32 rois x 49 bins, 16 planes each ----
    for (int it = tid; it < kNROI * kNBIN; it += kTPB) {
        const int r = it / kNBIN;
        const int bin = it - r * kNBIN;
        const int ph = bin / kPW;
        const int pw = bin - ph * kPW;
        const int bofs = sbidx[r] << 4;                    // batch offset in cell
        const int yk = r * kNSAMP + ph * kSR;
        const int xk = r * kNSAMP + pw * kSR;

        const int   ry[4] = { syi0[yk], syi1[yk], syi0[yk + 1], syi1[yk + 1] };
        const float wy[4] = { syw0[yk], syw1[yk], syw0[yk + 1], syw1[yk + 1] };
        const int   cx[4] = { sxi0[xk], sxi1[xk], sxi0[xk + 1], sxi1[xk + 1] };
        const float wx[4] = { sxw0[xk], sxw1[xk], sxw0[xk + 1], sxw1[xk + 1] };

        int rowoff[4], coloff[4];
        #pragma unroll
        for (int i = 0; i < 4; ++i) rowoff[i] = ry[i] * (16 * kCSTR) + bofs;
        #pragma unroll
        for (int j = 0; j < 4; ++j) coloff[j] = cx[j] * kCSTR;

        float4 acc[4] = {};
        #pragma unroll
        for (int i = 0; i < 4; ++i) {
            #pragma unroll
            for (int j = 0; j < 4; ++j) {
                const float w = wy[i] * wx[j];
                const float* cellp = &sp[rowoff[i] + coloff[j]];
                #pragma unroll
                for (int pg = 0; pg < 4; ++pg) {
                    const float4 v = *reinterpret_cast<const float4*>(cellp + pg * 4);
                    acc[pg].x += w * v.x;
                    acc[pg].y += w * v.y;
                    acc[pg].z += w * v.z;
                    acc[pg].w += w * v.w;
                }
            }
        }

        float* dst = out + (size_t)(r * kCL + cl0) * kNBIN + bin;
        #pragma unroll
        for (int pg = 0; pg < 4; ++pg) {
            dst[(pg * 4 + 0) * kNBIN] = acc[pg].x;
            dst[(pg * 4 + 1) * kNBIN] = acc[pg].y;
            dst[(pg * 4 + 2) * kNBIN] = acc[pg].z;
            dst[(pg * 4 + 3) * kNBIN] = acc[pg].w;
        }
    }
}

extern "C" void kernel_launch(void* const* d_in, const int* in_sizes, int n_in,
                              void* d_out, int out_size, void* d_ws, size_t ws_size,
                              hipStream_t stream) {
    const float* input = (const float*)d_in[0];
    const float* rois  = (const float*)d_in[1];
    float* out = (float*)d_out;
    roialign3d_kernel<<<dim3(kCL / kPPB), dim3(kTPB), 0, stream>>>(input, rois, out);
}